// Round 1
// baseline (1289.754 us; speedup 1.0000x reference)
//
#include <hip/hip_runtime.h>
#include <math.h>

#define Bv   32
#define Nv   1024
#define Dv   768
#define Cv   201
#define Kv   5
#define CKv  1005
#define BNv  32768
#define NCLS 200

// output offsets (floats)
#define OFF_CL     0
#define OFF_IPL    6400
#define OFF_LOG    38560
#define OFF_PART   32970400
#define OFF_PNEW   33003168
#define OFF_PSEUDO 33775008

// ---------------------------------------------------------------- zero ws
__global__ __launch_bounds__(256) void zero_kernel(int* __restrict__ p, int n) {
  int i = blockIdx.x * 256 + threadIdx.x;
  if (i < n) p[i] = 0;
}

// ------------------------------------------------------- row inverse norms
// rows: [0,BN) -> patch_tokens, [BN,2BN) -> raw, [2BN,2BN+CK) -> prototypes
__global__ __launch_bounds__(256) void rownorms_kernel(
    const float* __restrict__ pt, const float* __restrict__ raw,
    const float* __restrict__ proto,
    float* __restrict__ inv_pt, float* __restrict__ inv_raw,
    float* __restrict__ inv_proto) {
  int row  = blockIdx.x * 4 + (threadIdx.x >> 6);
  int lane = threadIdx.x & 63;
  const float* src;
  float* dst;
  if (row < BNv)            { src = pt    + (size_t)row * Dv;          dst = inv_pt    + row; }
  else if (row < 2 * BNv)   { int r = row - BNv;     src = raw   + (size_t)r * Dv; dst = inv_raw   + r; }
  else if (row < 2 * BNv + CKv) { int r = row - 2 * BNv; src = proto + (size_t)r * Dv; dst = inv_proto + r; }
  else return;
  float s = 0.f;
#pragma unroll
  for (int i = 0; i < 3; ++i) {
    float4 v = *reinterpret_cast<const float4*>(src + (i * 64 + lane) * 4);
    s += v.x * v.x + v.y * v.y + v.z * v.z + v.w * v.w;
  }
#pragma unroll
  for (int off = 32; off > 0; off >>= 1) s += __shfl_xor(s, off);
  if (lane == 0) *dst = 1.0f / fmaxf(sqrtf(s), 1e-12f);
}

// ------------------------------------------------------------------- GEMM
// C[m][n] = inv_a[m]*inv_b[n] * dot(A[m,:], B[n,:])   (A:[32768,768], B:[1005,768])
#define TM 128
#define TN 64
#define TK 32
#define LDA_ (TM + 4)
#define LDB_ (TN + 4)
__global__ __launch_bounds__(256) void gemm_logits_kernel(
    const float* __restrict__ A, const float* __restrict__ Bm,
    const float* __restrict__ inv_a, const float* __restrict__ inv_b,
    float* __restrict__ Co) {
  __shared__ float As[TK][LDA_];
  __shared__ float Bs[TK][LDB_];
  const int m0 = blockIdx.x * TM;
  const int n0 = blockIdx.y * TN;
  const int tid = threadIdx.x;
  const int tx = tid & 15;   // n direction, 4 cols each
  const int ty = tid >> 4;   // m direction, 8 rows each
  float acc[8][4] = {};

  for (int k0 = 0; k0 < Dv; k0 += TK) {
    // stage A tile 128x32 (transposed into As[k][m])
#pragma unroll
    for (int l = 0; l < 4; ++l) {
      int i  = tid + l * 256;       // 0..1023
      int r  = i >> 3;              // 0..127
      int c4 = i & 7;               // 0..7
      float4 v = *reinterpret_cast<const float4*>(A + (size_t)(m0 + r) * Dv + k0 + c4 * 4);
      As[c4 * 4 + 0][r] = v.x;
      As[c4 * 4 + 1][r] = v.y;
      As[c4 * 4 + 2][r] = v.z;
      As[c4 * 4 + 3][r] = v.w;
    }
    // stage B tile 64x32 (transposed into Bs[k][n]), guard n >= 1005
#pragma unroll
    for (int l = 0; l < 2; ++l) {
      int i  = tid + l * 256;       // 0..511
      int r  = i >> 3;              // 0..63
      int c4 = i & 7;
      int gn = n0 + r;
      float4 v = make_float4(0.f, 0.f, 0.f, 0.f);
      if (gn < CKv) v = *reinterpret_cast<const float4*>(Bm + (size_t)gn * Dv + k0 + c4 * 4);
      Bs[c4 * 4 + 0][r] = v.x;
      Bs[c4 * 4 + 1][r] = v.y;
      Bs[c4 * 4 + 2][r] = v.z;
      Bs[c4 * 4 + 3][r] = v.w;
    }
    __syncthreads();
#pragma unroll
    for (int kk = 0; kk < TK; ++kk) {
      float a[8], b[4];
      *reinterpret_cast<float4*>(&a[0]) = *reinterpret_cast<const float4*>(&As[kk][ty * 8]);
      *reinterpret_cast<float4*>(&a[4]) = *reinterpret_cast<const float4*>(&As[kk][ty * 8 + 4]);
      *reinterpret_cast<float4*>(&b[0]) = *reinterpret_cast<const float4*>(&Bs[kk][tx * 4]);
#pragma unroll
      for (int i = 0; i < 8; ++i)
#pragma unroll
        for (int j = 0; j < 4; ++j) acc[i][j] = fmaf(a[i], b[j], acc[i][j]);
    }
    __syncthreads();
  }
  // epilogue: scale by inverse norms, bounds-checked store
#pragma unroll
  for (int i = 0; i < 8; ++i) {
    int m = m0 + ty * 8 + i;
    float ia = inv_a[m];
#pragma unroll
    for (int j = 0; j < 4; ++j) {
      int n = n0 + tx * 4 + j;
      if (n < CKv) Co[(size_t)m * CKv + n] = acc[i][j] * ia * inv_b[n];
    }
  }
}

// ---------------------- image_prototype_logits (max over n) + class_logits
__global__ __launch_bounds__(256) void ipl_kernel(
    const float* __restrict__ logits, const float* __restrict__ sa_w,
    float* __restrict__ out) {
  const int c = blockIdx.x;  // 0..200
  const int b = blockIdx.y;  // 0..31
  const int tid = threadIdx.x;
  float mx[Kv];
#pragma unroll
  for (int k = 0; k < Kv; ++k) mx[k] = -INFINITY;
  for (int n = tid; n < Nv; n += 256) {
    const float* p = logits + (size_t)(b * Nv + n) * CKv + c * Kv;
#pragma unroll
    for (int k = 0; k < Kv; ++k) mx[k] = fmaxf(mx[k], p[k]);
  }
#pragma unroll
  for (int off = 32; off > 0; off >>= 1)
#pragma unroll
    for (int k = 0; k < Kv; ++k) mx[k] = fmaxf(mx[k], __shfl_xor(mx[k], off));
  __shared__ float red[4][Kv];
  int wave = tid >> 6, lane = tid & 63;
  if (lane == 0)
#pragma unroll
    for (int k = 0; k < Kv; ++k) red[wave][k] = mx[k];
  __syncthreads();
  if (tid == 0) {
    float r[Kv];
#pragma unroll
    for (int k = 0; k < Kv; ++k)
      r[k] = fmaxf(fmaxf(red[0][k], red[1][k]), fmaxf(red[2][k], red[3][k]));
#pragma unroll
    for (int k = 0; k < Kv; ++k) out[OFF_IPL + (size_t)(b * Cv + c) * Kv + k] = r[k];
    if (c < NCLS) {
      // saw = softmax(sa_weights[c]) * K
      float w[Kv], wm = -INFINITY;
#pragma unroll
      for (int k = 0; k < Kv; ++k) { w[k] = sa_w[c * Kv + k]; wm = fmaxf(wm, w[k]); }
      float es = 0.f;
#pragma unroll
      for (int k = 0; k < Kv; ++k) { w[k] = expf(w[k] - wm); es += w[k]; }
      float cl = 0.f;
#pragma unroll
      for (int k = 0; k < Kv; ++k) cl += r[k] * (w[k] / es * (float)Kv);
      out[OFF_CL + b * NCLS + c] = cl / 0.2f;
    }
  }
}

// ------------------- per-token pseudo label, softmax, argmax, threshold, A
__global__ __launch_bounds__(256) void assign_kernel(
    const float* __restrict__ logits, const int* __restrict__ labels,
    const int* __restrict__ sam, float* __restrict__ out,
    float* __restrict__ A_buf, int* __restrict__ tok_lab,
    int* __restrict__ present) {
  int n = blockIdx.x * 256 + threadIdx.x;
  if (n >= BNv) return;
  int b = n >> 10;
  int lab = (sam[n] == 1) ? labels[b] : NCLS;
  out[OFF_PSEUDO + n] = (float)lab;
  const float* p = logits + (size_t)n * CKv + lab * Kv;
  float L[Kv];
#pragma unroll
  for (int k = 0; k < Kv; ++k) L[k] = p[k];
  float mv = L[0];
  int idx = 0;
#pragma unroll
  for (int k = 1; k < Kv; ++k)
    if (L[k] > mv) { mv = L[k]; idx = k; }
  out[OFF_PART + n] = (float)(idx + lab * Kv);
  float e[Kv], s = 0.f;
#pragma unroll
  for (int k = 0; k < Kv; ++k) { e[k] = expf(L[k] - mv); s += e[k]; }
  float inv = 1.0f / s;      // max softmax value = exp(0)/s = inv
  float scale = (inv < 0.8f) ? 0.f : inv;
#pragma unroll
  for (int k = 0; k < Kv; ++k) A_buf[(size_t)n * Kv + k] = e[k] * scale;
  tok_lab[n] = lab;
  present[lab] = 1;  // benign race: all writers store 1
}

// --------------------------------------- per-class centroid accumulation
// block = (image b, d-chunk). Each image feeds exactly 2 classes: labels[b], 200.
__global__ __launch_bounds__(256) void accum_kernel(
    const float* __restrict__ raw, const float* __restrict__ inv_raw,
    const float* __restrict__ A_buf, const int* __restrict__ tok_lab,
    const int* __restrict__ labels, float* __restrict__ P_acc) {
  const int b = blockIdx.x;                  // 0..31
  const int d = blockIdx.y * 256 + threadIdx.x;  // 0..767
  __shared__ float As[256][Kv];
  __shared__ int   Ls[256];
  float accL[Kv] = {}, accB[Kv] = {};
  for (int t0 = 0; t0 < Nv; t0 += 256) {
    int n = b * Nv + t0 + threadIdx.x;
#pragma unroll
    for (int k = 0; k < Kv; ++k) As[threadIdx.x][k] = A_buf[(size_t)n * Kv + k];
    Ls[threadIdx.x] = tok_lab[n];
    __syncthreads();
    for (int t = 0; t < 256; ++t) {
      int n2 = b * Nv + t0 + t;
      float rv = raw[(size_t)n2 * Dv + d] * inv_raw[n2];
      if (Ls[t] == NCLS) {   // uniform branch across block
#pragma unroll
        for (int k = 0; k < Kv; ++k) accB[k] = fmaf(As[t][k], rv, accB[k]);
      } else {
#pragma unroll
        for (int k = 0; k < Kv; ++k) accL[k] = fmaf(As[t][k], rv, accL[k]);
      }
    }
    __syncthreads();
  }
  int lab = labels[b];
#pragma unroll
  for (int k = 0; k < Kv; ++k) atomicAdd(&P_acc[((size_t)lab * Kv + k) * Dv + d], accL[k]);
#pragma unroll
  for (int k = 0; k < Kv; ++k) atomicAdd(&P_acc[((size_t)NCLS * Kv + k) * Dv + d], accB[k]);
}

// ------------------------------------------------------------ EMA update
__global__ __launch_bounds__(256) void pnew_kernel(
    const float* __restrict__ proto, const float* __restrict__ P_acc,
    const int* __restrict__ present, float* __restrict__ out) {
  int i = blockIdx.x * 256 + threadIdx.x;
  if (i >= Cv * Kv * Dv) return;
  int c = i / (Kv * Dv);
  float p = proto[i];
  out[OFF_PNEW + i] = present[c] ? 0.999f * p + 0.001f * P_acc[i] : p;
}

// -------------------------------------------------------------- launcher
extern "C" void kernel_launch(void* const* d_in, const int* in_sizes, int n_in,
                              void* d_out, int out_size, void* d_ws, size_t ws_size,
                              hipStream_t stream) {
  const float* pt    = (const float*)d_in[0];
  const float* raw   = (const float*)d_in[1];
  const float* proto = (const float*)d_in[2];
  const float* sa_w  = (const float*)d_in[3];
  const int*   labels = (const int*)d_in[4];
  const int*   sam    = (const int*)d_in[5];
  float* out = (float*)d_out;

  // workspace layout
  float* inv_pt    = (float*)d_ws;
  float* inv_raw   = inv_pt + BNv;
  float* inv_proto = inv_raw + BNv;
  float* A_buf     = inv_proto + 1008;           // pad
  int*   tok_lab   = (int*)(A_buf + (size_t)BNv * Kv);
  float* P_acc     = (float*)(tok_lab + BNv);
  int*   present   = (int*)(P_acc + (size_t)Cv * Kv * Dv);

  // zero P_acc + present (contiguous)
  int nz = Cv * Kv * Dv + Cv;
  zero_kernel<<<(nz + 255) / 256, 256, 0, stream>>>((int*)P_acc, nz);

  rownorms_kernel<<<(2 * BNv + CKv + 3) / 4, 256, 0, stream>>>(
      pt, raw, proto, inv_pt, inv_raw, inv_proto);

  gemm_logits_kernel<<<dim3(BNv / TM, (CKv + TN - 1) / TN), 256, 0, stream>>>(
      pt, proto, inv_pt, inv_proto, out + OFF_LOG);

  ipl_kernel<<<dim3(Cv, Bv), 256, 0, stream>>>(out + OFF_LOG, sa_w, out);

  assign_kernel<<<BNv / 256, 256, 0, stream>>>(
      out + OFF_LOG, labels, sam, out, A_buf, tok_lab, present);

  accum_kernel<<<dim3(Bv, Dv / 256), 256, 0, stream>>>(
      raw, inv_raw, A_buf, tok_lab, labels, P_acc);

  pnew_kernel<<<(Cv * Kv * Dv + 255) / 256, 256, 0, stream>>>(
      proto, P_acc, present, out);
}

// Round 2
// 406.814 us; speedup vs baseline: 3.1704x; 3.1704x over previous
//
#include <hip/hip_runtime.h>
#include <math.h>

#define Bv   32
#define Nv   1024
#define Dv   768
#define Cv   201
#define Kv   5
#define CKv  1005
#define BNv  32768
#define NCLS 200

// output offsets (floats)
#define OFF_CL     0
#define OFF_IPL    6400
#define OFF_LOG    38560
#define OFF_PART   32970400
#define OFF_PNEW   33003168
#define OFF_PSEUDO 33775008

typedef short bf16x8 __attribute__((ext_vector_type(8)));
typedef float f32x4  __attribute__((ext_vector_type(4)));
typedef __attribute__((address_space(1))) const unsigned int g_u32;
typedef __attribute__((address_space(3))) unsigned int l_u32;

__device__ inline unsigned short f2bf(float f) {
  unsigned u = __float_as_uint(f);
  u += 0x7fffu + ((u >> 16) & 1u);     // RNE
  return (unsigned short)(u >> 16);
}
__device__ inline float bf2f(unsigned short h) {
  return __uint_as_float(((unsigned)h) << 16);
}
// order-preserving float<->uint for atomicMax
__device__ inline unsigned fenc(float f) {
  unsigned u = __float_as_uint(f);
  return u ^ (((unsigned)((int)u >> 31)) | 0x80000000u);
}
__device__ inline float fdec(unsigned u) {
  unsigned bits = (u & 0x80000000u) ? (u ^ 0x80000000u) : ~u;
  return __uint_as_float(bits);
}

// ---------------------------------------------------------------- zero ws
__global__ __launch_bounds__(256) void zero_kernel(int* __restrict__ p, int n) {
  int i = blockIdx.x * 256 + threadIdx.x;
  if (i < n) p[i] = 0;
}

// ------------------------------------------------------- row inverse norms
__global__ __launch_bounds__(256) void rownorms_kernel(
    const float* __restrict__ pt, const float* __restrict__ raw,
    const float* __restrict__ proto,
    float* __restrict__ inv_pt, float* __restrict__ inv_raw,
    float* __restrict__ inv_proto) {
  int row  = blockIdx.x * 4 + (threadIdx.x >> 6);
  int lane = threadIdx.x & 63;
  const float* src;
  float* dst;
  if (row < BNv)            { src = pt    + (size_t)row * Dv;          dst = inv_pt    + row; }
  else if (row < 2 * BNv)   { int r = row - BNv;     src = raw   + (size_t)r * Dv; dst = inv_raw   + r; }
  else if (row < 2 * BNv + CKv) { int r = row - 2 * BNv; src = proto + (size_t)r * Dv; dst = inv_proto + r; }
  else return;
  float s = 0.f;
#pragma unroll
  for (int i = 0; i < 3; ++i) {
    float4 v = *reinterpret_cast<const float4*>(src + (i * 64 + lane) * 4);
    s += v.x * v.x + v.y * v.y + v.z * v.z + v.w * v.w;
  }
#pragma unroll
  for (int off = 32; off > 0; off >>= 1) s += __shfl_xor(s, off);
  if (lane == 0) *dst = 1.0f / fmaxf(sqrtf(s), 1e-12f);
}

// ------------------------------------------- split f32 -> bf16 hi/lo pair
__global__ __launch_bounds__(256) void prep_split_kernel(
    const float* __restrict__ pt, const float* __restrict__ proto,
    unsigned short* __restrict__ Ah, unsigned short* __restrict__ Al,
    unsigned short* __restrict__ Bh, unsigned short* __restrict__ Bl) {
  const long ACH = (long)BNv * Dv / 4;     // 6291456
  const long BCH = (long)1024 * Dv / 4;    // 196608
  long idx = (long)blockIdx.x * 256 + threadIdx.x;
  float4 v;
  unsigned short *ph, *pl;
  if (idx < ACH) {
    v = reinterpret_cast<const float4*>(pt)[idx];
    ph = Ah + idx * 4; pl = Al + idx * 4;
  } else if (idx < ACH + BCH) {
    long j = idx - ACH;
    long row = j / 192;                    // 768/4
    if (row < CKv) v = reinterpret_cast<const float4*>(proto)[j];
    else           v = make_float4(0.f, 0.f, 0.f, 0.f);
    ph = Bh + j * 4; pl = Bl + j * 4;
  } else return;
  float a[4] = {v.x, v.y, v.z, v.w};
  unsigned short hh[4], ll[4];
#pragma unroll
  for (int i = 0; i < 4; ++i) {
    hh[i] = f2bf(a[i]);
    ll[i] = f2bf(a[i] - bf2f(hh[i]));
  }
  *reinterpret_cast<ushort4*>(ph) = make_ushort4(hh[0], hh[1], hh[2], hh[3]);
  *reinterpret_cast<ushort4*>(pl) = make_ushort4(ll[0], ll[1], ll[2], ll[3]);
}

// ------------------------------------------------- MFMA split-bf16 GEMM
// logits[m][n] = inv_a[m]*inv_b[n] * dot(A[m,:],B[n,:]); fused col-max -> iplU
#define GM 128
#define GN 128
#define GK 32
__global__ __launch_bounds__(256) void gemm_mfma_kernel(
    const unsigned short* __restrict__ Ah, const unsigned short* __restrict__ Al,
    const unsigned short* __restrict__ Bh, const unsigned short* __restrict__ Bl,
    const float* __restrict__ inv_a, const float* __restrict__ inv_b,
    float* __restrict__ Co, unsigned int* __restrict__ iplU) {
  __shared__ __align__(16) unsigned short lA[2][GM][GK];
  __shared__ __align__(16) unsigned short lB[2][GN][GK];
  const int tid  = threadIdx.x;
  const int wid  = tid >> 6;
  const int lane = tid & 63;
  const int wm = wid >> 1, wn = wid & 1;
  const int m0 = blockIdx.x * GM, n0 = blockIdx.y * GN;

  f32x4 acc[4][4];
#pragma unroll
  for (int i = 0; i < 4; ++i)
#pragma unroll
    for (int j = 0; j < 4; ++j)
#pragma unroll
      for (int r = 0; r < 4; ++r) acc[i][j][r] = 0.f;

  const int srow = (lane >> 2);        // 0..15 within 16-row chunk
  const int skc  = (lane & 3) * 8;     // k offset in shorts

  for (int k0 = 0; k0 < Dv; k0 += GK) {
#pragma unroll
    for (int c = 0; c < 2; ++c) {
      int ch = wid * 2 + c;            // 0..7
      int rA = m0 + ch * 16 + srow;
      int rB = n0 + ch * 16 + srow;
      const unsigned short* sAh = Ah + (size_t)rA * Dv + k0 + skc;
      const unsigned short* sAl = Al + (size_t)rA * Dv + k0 + skc;
      const unsigned short* sBh = Bh + (size_t)rB * Dv + k0 + skc;
      const unsigned short* sBl = Bl + (size_t)rB * Dv + k0 + skc;
      __builtin_amdgcn_global_load_lds((g_u32*)sAh, (l_u32*)&lA[0][ch * 16][0], 16, 0, 0);
      __builtin_amdgcn_global_load_lds((g_u32*)sAl, (l_u32*)&lA[1][ch * 16][0], 16, 0, 0);
      __builtin_amdgcn_global_load_lds((g_u32*)sBh, (l_u32*)&lB[0][ch * 16][0], 16, 0, 0);
      __builtin_amdgcn_global_load_lds((g_u32*)sBl, (l_u32*)&lB[1][ch * 16][0], 16, 0, 0);
    }
    __syncthreads();

    const int fr = lane & 15;
    const int fq = (lane >> 4) * 8;    // k offset in shorts for frag read
    bf16x8 ah[4], al[4], bh[4], bl[4];
#pragma unroll
    for (int i = 0; i < 4; ++i) {
      ah[i] = *reinterpret_cast<const bf16x8*>(&lA[0][wm * 64 + i * 16 + fr][fq]);
      al[i] = *reinterpret_cast<const bf16x8*>(&lA[1][wm * 64 + i * 16 + fr][fq]);
      bh[i] = *reinterpret_cast<const bf16x8*>(&lB[0][wn * 64 + i * 16 + fr][fq]);
      bl[i] = *reinterpret_cast<const bf16x8*>(&lB[1][wn * 64 + i * 16 + fr][fq]);
    }
#pragma unroll
    for (int i = 0; i < 4; ++i)
#pragma unroll
      for (int j = 0; j < 4; ++j) {
        acc[i][j] = __builtin_amdgcn_mfma_f32_16x16x32_bf16(ah[i], bh[j], acc[i][j], 0, 0, 0);
        acc[i][j] = __builtin_amdgcn_mfma_f32_16x16x32_bf16(ah[i], bl[j], acc[i][j], 0, 0, 0);
        acc[i][j] = __builtin_amdgcn_mfma_f32_16x16x32_bf16(al[i], bh[j], acc[i][j], 0, 0, 0);
      }
    __syncthreads();
  }

  // epilogue: scale by norms, store, fused column-max for ipl
  const int b_img = m0 >> 10;
  const int mbase = m0 + wm * 64 + ((lane >> 4) * 4);
  float ia[4][4];
#pragma unroll
  for (int i = 0; i < 4; ++i)
#pragma unroll
    for (int r = 0; r < 4; ++r) ia[i][r] = inv_a[mbase + i * 16 + r];

#pragma unroll
  for (int j = 0; j < 4; ++j) {
    int n = n0 + wn * 64 + j * 16 + (lane & 15);
    bool ok = (n < CKv);
    float ib = ok ? inv_b[n] : 0.f;
    float cmax = -INFINITY;
#pragma unroll
    for (int i = 0; i < 4; ++i) {
      float vals[4];
#pragma unroll
      for (int r = 0; r < 4; ++r) {
        float v = acc[i][j][r] * ia[i][r] * ib;
        vals[r] = v;
        cmax = fmaxf(cmax, v);
      }
      if (ok) {
#pragma unroll
        for (int r = 0; r < 4; ++r)
          Co[(size_t)(mbase + i * 16 + r) * CKv + n] = vals[r];
      }
    }
    cmax = fmaxf(cmax, __shfl_xor(cmax, 16));
    cmax = fmaxf(cmax, __shfl_xor(cmax, 32));
    if (lane < 16 && ok)
      atomicMax(&iplU[(size_t)b_img * 1024 + n], fenc(cmax));
  }
}

// ---------------------------- finalize ipl + class_logits from atomic maxes
__global__ __launch_bounds__(256) void ipl_final_kernel(
    const unsigned int* __restrict__ iplU, const float* __restrict__ sa_w,
    float* __restrict__ out) {
  int b = blockIdx.x;
  int c = threadIdx.x;
  if (c >= Cv) return;
  float r[Kv];
#pragma unroll
  for (int k = 0; k < Kv; ++k) {
    r[k] = fdec(iplU[(size_t)b * 1024 + c * Kv + k]);
    out[OFF_IPL + (size_t)(b * Cv + c) * Kv + k] = r[k];
  }
  if (c < NCLS) {
    float w[Kv], wm = -INFINITY;
#pragma unroll
    for (int k = 0; k < Kv; ++k) { w[k] = sa_w[c * Kv + k]; wm = fmaxf(wm, w[k]); }
    float es = 0.f;
#pragma unroll
    for (int k = 0; k < Kv; ++k) { w[k] = expf(w[k] - wm); es += w[k]; }
    float cl = 0.f;
#pragma unroll
    for (int k = 0; k < Kv; ++k) cl += r[k] * (w[k] / es * (float)Kv);
    out[OFF_CL + b * NCLS + c] = cl / 0.2f;
  }
}

// ------------------- per-token pseudo label, softmax, argmax, threshold, A
__global__ __launch_bounds__(256) void assign_kernel(
    const float* __restrict__ logits, const int* __restrict__ labels,
    const int* __restrict__ sam, float* __restrict__ out,
    float* __restrict__ A_buf, int* __restrict__ tok_lab,
    int* __restrict__ present) {
  int n = blockIdx.x * 256 + threadIdx.x;
  if (n >= BNv) return;
  int b = n >> 10;
  int lab = (sam[n] == 1) ? labels[b] : NCLS;
  out[OFF_PSEUDO + n] = (float)lab;
  const float* p = logits + (size_t)n * CKv + lab * Kv;
  float L[Kv];
#pragma unroll
  for (int k = 0; k < Kv; ++k) L[k] = p[k];
  float mv = L[0];
  int idx = 0;
#pragma unroll
  for (int k = 1; k < Kv; ++k)
    if (L[k] > mv) { mv = L[k]; idx = k; }
  out[OFF_PART + n] = (float)(idx + lab * Kv);
  float e[Kv], s = 0.f;
#pragma unroll
  for (int k = 0; k < Kv; ++k) { e[k] = expf(L[k] - mv); s += e[k]; }
  float inv = 1.0f / s;
  float scale = (inv < 0.8f) ? 0.f : inv;
#pragma unroll
  for (int k = 0; k < Kv; ++k) A_buf[(size_t)n * Kv + k] = e[k] * scale;
  tok_lab[n] = lab;
  present[lab] = 1;
}

// --------------------------------------- per-class centroid accumulation
// grid (32 b, 3 d-chunks of 256, 4 n-chunks of 256)
__global__ __launch_bounds__(256) void accum_kernel(
    const float* __restrict__ raw, const float* __restrict__ inv_raw,
    const float* __restrict__ A_buf, const int* __restrict__ tok_lab,
    const int* __restrict__ labels, float* __restrict__ P_acc) {
  const int b = blockIdx.x;
  const int d = blockIdx.y * 256 + threadIdx.x;
  const int t0 = blockIdx.z * 256;
  __shared__ float As[256][Kv];
  __shared__ float Sc[256];
  __shared__ int   Ls[256];
  {
    int n = b * Nv + t0 + threadIdx.x;
#pragma unroll
    for (int k = 0; k < Kv; ++k) As[threadIdx.x][k] = A_buf[(size_t)n * Kv + k];
    Ls[threadIdx.x] = tok_lab[n];
    Sc[threadIdx.x] = inv_raw[n];
  }
  __syncthreads();
  float accL[Kv] = {}, accB[Kv] = {};
  for (int t = 0; t < 256; ++t) {
    int n2 = b * Nv + t0 + t;
    float rv = raw[(size_t)n2 * Dv + d] * Sc[t];
    if (Ls[t] == NCLS) {
#pragma unroll
      for (int k = 0; k < Kv; ++k) accB[k] = fmaf(As[t][k], rv, accB[k]);
    } else {
#pragma unroll
      for (int k = 0; k < Kv; ++k) accL[k] = fmaf(As[t][k], rv, accL[k]);
    }
  }
  int lab = labels[b];
#pragma unroll
  for (int k = 0; k < Kv; ++k) atomicAdd(&P_acc[((size_t)lab * Kv + k) * Dv + d], accL[k]);
#pragma unroll
  for (int k = 0; k < Kv; ++k) atomicAdd(&P_acc[((size_t)NCLS * Kv + k) * Dv + d], accB[k]);
}

// ------------------------------------------------------------ EMA update
__global__ __launch_bounds__(256) void pnew_kernel(
    const float* __restrict__ proto, const float* __restrict__ P_acc,
    const int* __restrict__ present, float* __restrict__ out) {
  int i = blockIdx.x * 256 + threadIdx.x;
  if (i >= Cv * Kv * Dv) return;
  int c = i / (Kv * Dv);
  float p = proto[i];
  out[OFF_PNEW + i] = present[c] ? 0.999f * p + 0.001f * P_acc[i] : p;
}

// ====================== fallback f32 GEMM path (small workspace) =========
#define TM 128
#define TN 64
#define TK 32
#define LDA_ (TM + 4)
#define LDB_ (TN + 4)
__global__ __launch_bounds__(256) void gemm_logits_kernel(
    const float* __restrict__ A, const float* __restrict__ Bm,
    const float* __restrict__ inv_a, const float* __restrict__ inv_b,
    float* __restrict__ Co) {
  __shared__ float As[TK][LDA_];
  __shared__ float Bs[TK][LDB_];
  const int m0 = blockIdx.x * TM;
  const int n0 = blockIdx.y * TN;
  const int tid = threadIdx.x;
  const int tx = tid & 15;
  const int ty = tid >> 4;
  float acc[8][4] = {};
  for (int k0 = 0; k0 < Dv; k0 += TK) {
#pragma unroll
    for (int l = 0; l < 4; ++l) {
      int i  = tid + l * 256;
      int r  = i >> 3;
      int c4 = i & 7;
      float4 v = *reinterpret_cast<const float4*>(A + (size_t)(m0 + r) * Dv + k0 + c4 * 4);
      As[c4 * 4 + 0][r] = v.x;
      As[c4 * 4 + 1][r] = v.y;
      As[c4 * 4 + 2][r] = v.z;
      As[c4 * 4 + 3][r] = v.w;
    }
#pragma unroll
    for (int l = 0; l < 2; ++l) {
      int i  = tid + l * 256;
      int r  = i >> 3;
      int c4 = i & 7;
      int gn = n0 + r;
      float4 v = make_float4(0.f, 0.f, 0.f, 0.f);
      if (gn < CKv) v = *reinterpret_cast<const float4*>(Bm + (size_t)gn * Dv + k0 + c4 * 4);
      Bs[c4 * 4 + 0][r] = v.x;
      Bs[c4 * 4 + 1][r] = v.y;
      Bs[c4 * 4 + 2][r] = v.z;
      Bs[c4 * 4 + 3][r] = v.w;
    }
    __syncthreads();
#pragma unroll
    for (int kk = 0; kk < TK; ++kk) {
      float a[8], bvals[4];
      *reinterpret_cast<float4*>(&a[0]) = *reinterpret_cast<const float4*>(&As[kk][ty * 8]);
      *reinterpret_cast<float4*>(&a[4]) = *reinterpret_cast<const float4*>(&As[kk][ty * 8 + 4]);
      *reinterpret_cast<float4*>(&bvals[0]) = *reinterpret_cast<const float4*>(&Bs[kk][tx * 4]);
#pragma unroll
      for (int i = 0; i < 8; ++i)
#pragma unroll
        for (int j = 0; j < 4; ++j) acc[i][j] = fmaf(a[i], bvals[j], acc[i][j]);
    }
    __syncthreads();
  }
#pragma unroll
  for (int i = 0; i < 8; ++i) {
    int m = m0 + ty * 8 + i;
    float iav = inv_a[m];
#pragma unroll
    for (int j = 0; j < 4; ++j) {
      int n = n0 + tx * 4 + j;
      if (n < CKv) Co[(size_t)m * CKv + n] = acc[i][j] * iav * inv_b[n];
    }
  }
}

__global__ __launch_bounds__(256) void ipl_kernel(
    const float* __restrict__ logits, const float* __restrict__ sa_w,
    float* __restrict__ out) {
  const int c = blockIdx.x;
  const int b = blockIdx.y;
  const int tid = threadIdx.x;
  float mx[Kv];
#pragma unroll
  for (int k = 0; k < Kv; ++k) mx[k] = -INFINITY;
  for (int n = tid; n < Nv; n += 256) {
    const float* p = logits + (size_t)(b * Nv + n) * CKv + c * Kv;
#pragma unroll
    for (int k = 0; k < Kv; ++k) mx[k] = fmaxf(mx[k], p[k]);
  }
#pragma unroll
  for (int off = 32; off > 0; off >>= 1)
#pragma unroll
    for (int k = 0; k < Kv; ++k) mx[k] = fmaxf(mx[k], __shfl_xor(mx[k], off));
  __shared__ float red[4][Kv];
  int wave = tid >> 6, lane = tid & 63;
  if (lane == 0)
#pragma unroll
    for (int k = 0; k < Kv; ++k) red[wave][k] = mx[k];
  __syncthreads();
  if (tid == 0) {
    float r[Kv];
#pragma unroll
    for (int k = 0; k < Kv; ++k)
      r[k] = fmaxf(fmaxf(red[0][k], red[1][k]), fmaxf(red[2][k], red[3][k]));
#pragma unroll
    for (int k = 0; k < Kv; ++k) out[OFF_IPL + (size_t)(b * Cv + c) * Kv + k] = r[k];
    if (c < NCLS) {
      float w[Kv], wm = -INFINITY;
#pragma unroll
      for (int k = 0; k < Kv; ++k) { w[k] = sa_w[c * Kv + k]; wm = fmaxf(wm, w[k]); }
      float es = 0.f;
#pragma unroll
      for (int k = 0; k < Kv; ++k) { w[k] = expf(w[k] - wm); es += w[k]; }
      float cl = 0.f;
#pragma unroll
      for (int k = 0; k < Kv; ++k) cl += r[k] * (w[k] / es * (float)Kv);
      out[OFF_CL + b * NCLS + c] = cl / 0.2f;
    }
  }
}

// -------------------------------------------------------------- launcher
extern "C" void kernel_launch(void* const* d_in, const int* in_sizes, int n_in,
                              void* d_out, int out_size, void* d_ws, size_t ws_size,
                              hipStream_t stream) {
  const float* pt     = (const float*)d_in[0];
  const float* raw    = (const float*)d_in[1];
  const float* proto  = (const float*)d_in[2];
  const float* sa_w   = (const float*)d_in[3];
  const int*   labels = (const int*)d_in[4];
  const int*   sam    = (const int*)d_in[5];
  float* out = (float*)d_out;

  // ---- workspace layout (floats) ----
  float* inv_pt    = (float*)d_ws;                       // 32768
  float* inv_raw   = inv_pt + BNv;                       // 32768
  float* inv_proto = inv_raw + BNv;                      // 1024 (pad)
  float* A_buf     = inv_proto + 1024;                   // 163840
  int*   tok_lab   = (int*)(A_buf + (size_t)BNv * Kv);   // 32768
  float* P_acc     = (float*)(tok_lab + BNv);            // 771840
  int*   present   = (int*)(P_acc + (size_t)Cv * Kv * Dv); // 256 (pad)
  unsigned int* iplU = (unsigned int*)(present + 256);   // 32768
  float* big_base  = (float*)(iplU + BNv);
  unsigned short* Ah = (unsigned short*)big_base;                    // 32768*768
  unsigned short* Al = Ah + (size_t)BNv * Dv;
  unsigned short* Bh = Al + (size_t)BNv * Dv;                        // 1024*768
  unsigned short* Bl = Bh + (size_t)1024 * Dv;
  size_t need = (size_t)((char*)(Bl + (size_t)1024 * Dv) - (char*)d_ws);

  // zero P_acc + present + iplU (contiguous)
  int nz = Cv * Kv * Dv + 256 + BNv;
  zero_kernel<<<(nz + 255) / 256, 256, 0, stream>>>((int*)P_acc, nz);

  rownorms_kernel<<<(2 * BNv + CKv + 3) / 4, 256, 0, stream>>>(
      pt, raw, proto, inv_pt, inv_raw, inv_proto);

  if (ws_size >= need) {
    // split-bf16 MFMA path
    const long ACH = (long)BNv * Dv / 4;
    const long BCH = (long)1024 * Dv / 4;
    prep_split_kernel<<<(int)((ACH + BCH + 255) / 256), 256, 0, stream>>>(
        pt, proto, Ah, Al, Bh, Bl);

    gemm_mfma_kernel<<<dim3(BNv / GM, 1024 / GN), 256, 0, stream>>>(
        Ah, Al, Bh, Bl, inv_pt, inv_proto, out + OFF_LOG, iplU);

    ipl_final_kernel<<<Bv, 256, 0, stream>>>(iplU, sa_w, out);
  } else {
    // fallback: f32 vector GEMM + separate max pass
    gemm_logits_kernel<<<dim3(BNv / TM, (CKv + TN - 1) / TN), 256, 0, stream>>>(
        pt, proto, inv_pt, inv_proto, out + OFF_LOG);
    ipl_kernel<<<dim3(Cv, Bv), 256, 0, stream>>>(out + OFF_LOG, sa_w, out);
  }

  assign_kernel<<<BNv / 256, 256, 0, stream>>>(
      out + OFF_LOG, labels, sam, out, A_buf, tok_lab, present);

  accum_kernel<<<dim3(Bv, Dv / 256, Nv / 256), 256, 0, stream>>>(
      raw, inv_raw, A_buf, tok_lab, labels, P_acc);

  pnew_kernel<<<(Cv * Kv * Dv + 255) / 256, 256, 0, stream>>>(
      proto, P_acc, present, out);
}

// Round 3
// 370.268 us; speedup vs baseline: 3.4833x; 1.0987x over previous
//
#include <hip/hip_runtime.h>
#include <math.h>

#define Bv   32
#define Nv   1024
#define Dv   768
#define Cv   201
#define Kv   5
#define CKv  1005
#define BNv  32768
#define NCLS 200

// output offsets (floats)
#define OFF_CL     0
#define OFF_IPL    6400
#define OFF_LOG    38560
#define OFF_PART   32970400
#define OFF_PNEW   33003168
#define OFF_PSEUDO 33775008

typedef short bf16x8 __attribute__((ext_vector_type(8)));
typedef float f32x4  __attribute__((ext_vector_type(4)));
typedef __attribute__((address_space(1))) const unsigned int g_u32;
typedef __attribute__((address_space(3))) unsigned int l_u32;

__device__ inline unsigned short f2bf(float f) {
  unsigned u = __float_as_uint(f);
  u += 0x7fffu + ((u >> 16) & 1u);     // RNE
  return (unsigned short)(u >> 16);
}
__device__ inline float bf2f(unsigned short h) {
  return __uint_as_float(((unsigned)h) << 16);
}
// order-preserving float<->uint for atomicMax
__device__ inline unsigned fenc(float f) {
  unsigned u = __float_as_uint(f);
  return u ^ (((unsigned)((int)u >> 31)) | 0x80000000u);
}
__device__ inline float fdec(unsigned u) {
  unsigned bits = (u & 0x80000000u) ? (u ^ 0x80000000u) : ~u;
  return __uint_as_float(bits);
}

// ---------------------------------------------------------------- zero ws
__global__ __launch_bounds__(256) void zero_kernel(int* __restrict__ p, int n) {
  int i = blockIdx.x * 256 + threadIdx.x;
  if (i < n) p[i] = 0;
}

// ---------------- fused: row norms + normalize + bf16 hi/lo split (interleaved)
// rows [0,BN): pt -> Ahl ; [BN, BN+1024): proto(pad) -> Bhl ; rest: raw -> inv_raw
// global layout: row stride 1536 shorts; d-block db (24): 64 shorts = hi k0..31 | lo k0..31
__global__ __launch_bounds__(256) void prep_kernel(
    const float* __restrict__ pt, const float* __restrict__ raw,
    const float* __restrict__ proto,
    unsigned short* __restrict__ Ahl, unsigned short* __restrict__ Bhl,
    float* __restrict__ inv_raw) {
  int row = blockIdx.x * 4 + (threadIdx.x >> 6);
  int l   = threadIdx.x & 63;
  const float* src;
  unsigned short* dst = nullptr;
  int mode;            // 0 = split-write, 2 = norm-only
  if (row < BNv) { src = pt + (size_t)row * Dv; dst = Ahl + (size_t)row * 1536; mode = 0; }
  else if (row < BNv + 1024) {
    int rp = row - BNv;
    dst = Bhl + (size_t)rp * 1536;
    if (rp < CKv) { src = proto + (size_t)rp * Dv; mode = 0; }
    else {           // zero-fill pad rows
      ushort4 z = make_ushort4(0, 0, 0, 0);
#pragma unroll
      for (int i = 0; i < 3; ++i) {
        int db = 8 * i + (l >> 3);
        int base = db * 64 + 4 * (l & 7);
        *reinterpret_cast<ushort4*>(dst + base)      = z;
        *reinterpret_cast<ushort4*>(dst + base + 32) = z;
      }
      return;
    }
  } else if (row < 2 * BNv + 1024) {
    int rr = row - BNv - 1024;
    src = raw + (size_t)rr * Dv;
    dst = nullptr; mode = 2;
    float s = 0.f;
#pragma unroll
    for (int i = 0; i < 3; ++i) {
      float4 v = reinterpret_cast<const float4*>(src)[i * 64 + l];
      s += v.x * v.x + v.y * v.y + v.z * v.z + v.w * v.w;
    }
#pragma unroll
    for (int off = 32; off > 0; off >>= 1) s += __shfl_xor(s, off);
    if (l == 0) inv_raw[rr] = 1.0f / fmaxf(sqrtf(s), 1e-12f);
    return;
  } else return;

  float4 v[3];
  float s = 0.f;
#pragma unroll
  for (int i = 0; i < 3; ++i) {
    v[i] = reinterpret_cast<const float4*>(src)[i * 64 + l];
    s += v[i].x * v[i].x + v[i].y * v[i].y + v[i].z * v[i].z + v[i].w * v[i].w;
  }
#pragma unroll
  for (int off = 32; off > 0; off >>= 1) s += __shfl_xor(s, off);
  float inv = 1.0f / fmaxf(sqrtf(s), 1e-12f);
#pragma unroll
  for (int i = 0; i < 3; ++i) {
    float a[4] = {v[i].x * inv, v[i].y * inv, v[i].z * inv, v[i].w * inv};
    unsigned short hh[4], ll[4];
#pragma unroll
    for (int t = 0; t < 4; ++t) {
      hh[t] = f2bf(a[t]);
      ll[t] = f2bf(a[t] - bf2f(hh[t]));
    }
    int db = 8 * i + (l >> 3);
    int base = db * 64 + 4 * (l & 7);
    *reinterpret_cast<ushort4*>(dst + base)      = make_ushort4(hh[0], hh[1], hh[2], hh[3]);
    *reinterpret_cast<ushort4*>(dst + base + 32) = make_ushort4(ll[0], ll[1], ll[2], ll[3]);
  }
}

// ------------------------------------------------- MFMA split-bf16 GEMM
// logits[m][n] = dot(Anorm[m,:], Bnorm[n,:]) via 3-pass split-bf16; fused col-max
// LDS rows 128B (8 x 16B slots), XOR swizzle slot^=(row&7) on BOTH source + read.
#define GM 128
#define GN 128
__global__ __launch_bounds__(256) void gemm_mfma_kernel(
    const unsigned short* __restrict__ Ahl, const unsigned short* __restrict__ Bhl,
    float* __restrict__ Co, unsigned int* __restrict__ iplU) {
  __shared__ __align__(16) unsigned short lA[GM][64];
  __shared__ __align__(16) unsigned short lB[GN][64];
  const int tid  = threadIdx.x;
  const int wid  = tid >> 6;
  const int lane = tid & 63;
  const int wm = wid >> 1, wn = wid & 1;
  const int m0 = blockIdx.x * GM, n0 = blockIdx.y * GN;

  f32x4 acc[4][4];
#pragma unroll
  for (int i = 0; i < 4; ++i)
#pragma unroll
    for (int j = 0; j < 4; ++j)
#pragma unroll
      for (int r = 0; r < 4; ++r) acc[i][j][r] = 0.f;

  const int srow = lane >> 3;               // row within 8-row segment
  const int sg   = (lane & 7) ^ srow;       // swizzled global slot
  const int fr   = lane & 15;
  const int q    = lane >> 4;
  const int sh = (q ^ (fr & 7)) * 8;        // hi slot offset (shorts), const per lane
  const int sl = (((q + 4)) ^ (fr & 7)) * 8;// lo slot offset

  for (int db = 0; db < 24; ++db) {
#pragma unroll
    for (int c = 0; c < 4; ++c) {
      int seg = wid * 4 + c;                // 0..15, 8 rows each
      const unsigned short* sA = Ahl + (size_t)(m0 + seg * 8 + srow) * 1536 + db * 64 + sg * 8;
      const unsigned short* sB = Bhl + (size_t)(n0 + seg * 8 + srow) * 1536 + db * 64 + sg * 8;
      __builtin_amdgcn_global_load_lds((g_u32*)sA, (l_u32*)&lA[seg * 8][0], 16, 0, 0);
      __builtin_amdgcn_global_load_lds((g_u32*)sB, (l_u32*)&lB[seg * 8][0], 16, 0, 0);
    }
    __syncthreads();

    bf16x8 ah[4], alo[4], bh[4], blo[4];
#pragma unroll
    for (int i = 0; i < 4; ++i) {
      const unsigned short* pa = &lA[wm * 64 + i * 16 + fr][0];
      ah[i]  = *reinterpret_cast<const bf16x8*>(pa + sh);
      alo[i] = *reinterpret_cast<const bf16x8*>(pa + sl);
      const unsigned short* pb = &lB[wn * 64 + i * 16 + fr][0];
      bh[i]  = *reinterpret_cast<const bf16x8*>(pb + sh);
      blo[i] = *reinterpret_cast<const bf16x8*>(pb + sl);
    }
#pragma unroll
    for (int i = 0; i < 4; ++i)
#pragma unroll
      for (int j = 0; j < 4; ++j) {
        acc[i][j] = __builtin_amdgcn_mfma_f32_16x16x32_bf16(ah[i],  bh[j],  acc[i][j], 0, 0, 0);
        acc[i][j] = __builtin_amdgcn_mfma_f32_16x16x32_bf16(ah[i],  blo[j], acc[i][j], 0, 0, 0);
        acc[i][j] = __builtin_amdgcn_mfma_f32_16x16x32_bf16(alo[i], bh[j],  acc[i][j], 0, 0, 0);
      }
    __syncthreads();
  }

  // epilogue: store + fused column-max for ipl
  const int b_img = m0 >> 10;
  const int mbase = m0 + wm * 64 + (lane >> 4) * 4;
#pragma unroll
  for (int j = 0; j < 4; ++j) {
    int n = n0 + wn * 64 + j * 16 + (lane & 15);
    bool ok = (n < CKv);
    float cmax = -INFINITY;
#pragma unroll
    for (int i = 0; i < 4; ++i) {
#pragma unroll
      for (int r = 0; r < 4; ++r) {
        float v = acc[i][j][r];
        cmax = fmaxf(cmax, v);
        if (ok) Co[(size_t)(mbase + i * 16 + r) * CKv + n] = v;
      }
    }
    cmax = fmaxf(cmax, __shfl_xor(cmax, 16));
    cmax = fmaxf(cmax, __shfl_xor(cmax, 32));
    if (lane < 16 && ok)
      atomicMax(&iplU[(size_t)b_img * 1024 + n], fenc(cmax));
  }
}

// ---------------------------- finalize ipl + class_logits from atomic maxes
__global__ __launch_bounds__(256) void ipl_final_kernel(
    const unsigned int* __restrict__ iplU, const float* __restrict__ sa_w,
    float* __restrict__ out) {
  int b = blockIdx.x;
  int c = threadIdx.x;
  if (c >= Cv) return;
  float r[Kv];
#pragma unroll
  for (int k = 0; k < Kv; ++k) {
    r[k] = fdec(iplU[(size_t)b * 1024 + c * Kv + k]);
    out[OFF_IPL + (size_t)(b * Cv + c) * Kv + k] = r[k];
  }
  if (c < NCLS) {
    float w[Kv], wm = -INFINITY;
#pragma unroll
    for (int k = 0; k < Kv; ++k) { w[k] = sa_w[c * Kv + k]; wm = fmaxf(wm, w[k]); }
    float es = 0.f;
#pragma unroll
    for (int k = 0; k < Kv; ++k) { w[k] = expf(w[k] - wm); es += w[k]; }
    float cl = 0.f;
#pragma unroll
    for (int k = 0; k < Kv; ++k) cl += r[k] * (w[k] / es * (float)Kv);
    out[OFF_CL + b * NCLS + c] = cl / 0.2f;
  }
}

// ------------------- per-token pseudo label, softmax, argmax, threshold, A
__global__ __launch_bounds__(256) void assign_kernel(
    const float* __restrict__ logits, const int* __restrict__ labels,
    const int* __restrict__ sam, float* __restrict__ out,
    float* __restrict__ A_buf, int* __restrict__ tok_lab,
    int* __restrict__ present) {
  int n = blockIdx.x * 256 + threadIdx.x;
  if (n >= BNv) return;
  int b = n >> 10;
  int lab = (sam[n] == 1) ? labels[b] : NCLS;
  out[OFF_PSEUDO + n] = (float)lab;
  const float* p = logits + (size_t)n * CKv + lab * Kv;
  float L[Kv];
#pragma unroll
  for (int k = 0; k < Kv; ++k) L[k] = p[k];
  float mv = L[0];
  int idx = 0;
#pragma unroll
  for (int k = 1; k < Kv; ++k)
    if (L[k] > mv) { mv = L[k]; idx = k; }
  out[OFF_PART + n] = (float)(idx + lab * Kv);
  float e[Kv], s = 0.f;
#pragma unroll
  for (int k = 0; k < Kv; ++k) { e[k] = expf(L[k] - mv); s += e[k]; }
  float inv = 1.0f / s;
  float scale = (inv < 0.8f) ? 0.f : inv;
#pragma unroll
  for (int k = 0; k < Kv; ++k) A_buf[(size_t)n * Kv + k] = e[k] * scale;
  tok_lab[n] = lab;
  present[lab] = 1;
}

// --------------------------------------- per-class centroid accumulation
// grid (32 b, 3 d-chunks of 256, 4 n-chunks of 256)
__global__ __launch_bounds__(256) void accum_kernel(
    const float* __restrict__ raw, const float* __restrict__ inv_raw,
    const float* __restrict__ A_buf, const int* __restrict__ tok_lab,
    const int* __restrict__ labels, float* __restrict__ P_acc) {
  const int b = blockIdx.x;
  const int d = blockIdx.y * 256 + threadIdx.x;
  const int t0 = blockIdx.z * 256;
  __shared__ float As[256][Kv];
  __shared__ float Sc[256];
  __shared__ int   Ls[256];
  {
    int n = b * Nv + t0 + threadIdx.x;
#pragma unroll
    for (int k = 0; k < Kv; ++k) As[threadIdx.x][k] = A_buf[(size_t)n * Kv + k];
    Ls[threadIdx.x] = tok_lab[n];
    Sc[threadIdx.x] = inv_raw[n];
  }
  __syncthreads();
  float accL[Kv] = {}, accB[Kv] = {};
#pragma unroll 4
  for (int t = 0; t < 256; ++t) {
    int n2 = b * Nv + t0 + t;
    float rv = raw[(size_t)n2 * Dv + d] * Sc[t];
    if (Ls[t] == NCLS) {
#pragma unroll
      for (int k = 0; k < Kv; ++k) accB[k] = fmaf(As[t][k], rv, accB[k]);
    } else {
#pragma unroll
      for (int k = 0; k < Kv; ++k) accL[k] = fmaf(As[t][k], rv, accL[k]);
    }
  }
  int lab = labels[b];
#pragma unroll
  for (int k = 0; k < Kv; ++k) atomicAdd(&P_acc[((size_t)lab * Kv + k) * Dv + d], accL[k]);
#pragma unroll
  for (int k = 0; k < Kv; ++k) atomicAdd(&P_acc[((size_t)NCLS * Kv + k) * Dv + d], accB[k]);
}

// ------------------------------------------------------------ EMA update
__global__ __launch_bounds__(256) void pnew_kernel(
    const float* __restrict__ proto, const float* __restrict__ P_acc,
    const int* __restrict__ present, float* __restrict__ out) {
  int i = blockIdx.x * 256 + threadIdx.x;
  if (i >= Cv * Kv * Dv) return;
  int c = i / (Kv * Dv);
  float p = proto[i];
  out[OFF_PNEW + i] = present[c] ? 0.999f * p + 0.001f * P_acc[i] : p;
}

// -------------------------------------------------------------- launcher
extern "C" void kernel_launch(void* const* d_in, const int* in_sizes, int n_in,
                              void* d_out, int out_size, void* d_ws, size_t ws_size,
                              hipStream_t stream) {
  const float* pt     = (const float*)d_in[0];
  const float* raw    = (const float*)d_in[1];
  const float* proto  = (const float*)d_in[2];
  const float* sa_w   = (const float*)d_in[3];
  const int*   labels = (const int*)d_in[4];
  const int*   sam    = (const int*)d_in[5];
  float* out = (float*)d_out;

  // ---- workspace layout ----
  float* A_buf   = (float*)d_ws;                           // 163840 f
  int*   tok_lab = (int*)(A_buf + (size_t)BNv * Kv);       // 32768 i
  float* P_acc   = (float*)(tok_lab + BNv);                // 771840 f
  int*   present = (int*)(P_acc + (size_t)Cv * Kv * Dv);   // 256 i (pad)
  unsigned int* iplU = (unsigned int*)(present + 256);     // 32768 u
  float* inv_raw = (float*)(iplU + BNv);                   // 32768 f
  unsigned short* Ahl = (unsigned short*)(inv_raw + BNv);  // 32768*1536 us
  unsigned short* Bhl = Ahl + (size_t)BNv * 1536;          // 1024*1536 us

  // zero P_acc + present + iplU (contiguous)
  int nz = Cv * Kv * Dv + 256 + BNv;
  zero_kernel<<<(nz + 255) / 256, 256, 0, stream>>>((int*)P_acc, nz);

  prep_kernel<<<(2 * BNv + 1024) / 4, 256, 0, stream>>>(
      pt, raw, proto, Ahl, Bhl, inv_raw);

  gemm_mfma_kernel<<<dim3(BNv / GM, 1024 / GN), 256, 0, stream>>>(
      Ahl, Bhl, out + OFF_LOG, iplU);

  ipl_final_kernel<<<Bv, 256, 0, stream>>>(iplU, sa_w, out);

  assign_kernel<<<BNv / 256, 256, 0, stream>>>(
      out + OFF_LOG, labels, sam, out, A_buf, tok_lab, present);

  accum_kernel<<<dim3(Bv, Dv / 256, Nv / 256), 256, 0, stream>>>(
      raw, inv_raw, A_buf, tok_lab, labels, P_acc);

  pnew_kernel<<<(Cv * Kv * Dv + 255) / 256, 256, 0, stream>>>(
      proto, P_acc, present, out);
}

// Round 4
// 332.429 us; speedup vs baseline: 3.8798x; 1.1138x over previous
//
#include <hip/hip_runtime.h>
#include <math.h>

#define Bv   32
#define Nv   1024
#define Dv   768
#define Cv   201
#define Kv   5
#define CKv  1005
#define BNv  32768
#define NCLS 200

// output offsets (floats)
#define OFF_CL     0
#define OFF_IPL    6400
#define OFF_LOG    38560
#define OFF_PART   32970400
#define OFF_PNEW   33003168
#define OFF_PSEUDO 33775008

typedef short bf16x8 __attribute__((ext_vector_type(8)));
typedef float f32x4  __attribute__((ext_vector_type(4)));
typedef __attribute__((address_space(1))) const unsigned int g_u32;
typedef __attribute__((address_space(3))) unsigned int l_u32;

__device__ inline unsigned short f2bf(float f) {
  unsigned u = __float_as_uint(f);
  u += 0x7fffu + ((u >> 16) & 1u);     // RNE
  return (unsigned short)(u >> 16);
}
__device__ inline float bf2f(unsigned short h) {
  return __uint_as_float(((unsigned)h) << 16);
}
// order-preserving float<->uint for atomicMax
__device__ inline unsigned fenc(float f) {
  unsigned u = __float_as_uint(f);
  return u ^ (((unsigned)((int)u >> 31)) | 0x80000000u);
}
__device__ inline float fdec(unsigned u) {
  unsigned bits = (u & 0x80000000u) ? (u ^ 0x80000000u) : ~u;
  return __uint_as_float(bits);
}

// ---------------------------------------------------------------- zero ws
__global__ __launch_bounds__(256) void zero_kernel(int* __restrict__ p, int n) {
  int i = blockIdx.x * 256 + threadIdx.x;
  if (i < n) p[i] = 0;
}

// ---------------- fused: row norms + normalize + bf16 split
// rows [0,BN): pt -> Ah (hi only, linear, 768 shorts/row)
// rows [BN, BN+1024): proto(pad) -> Bhl (hi|lo interleaved, 1536 shorts/row)
// rows [BN+1024, 2BN+1024): raw -> inv_raw
__global__ __launch_bounds__(256) void prep_kernel(
    const float* __restrict__ pt, const float* __restrict__ raw,
    const float* __restrict__ proto,
    unsigned short* __restrict__ Ah, unsigned short* __restrict__ Bhl,
    float* __restrict__ inv_raw) {
  int row = blockIdx.x * 4 + (threadIdx.x >> 6);
  int l   = threadIdx.x & 63;

  if (row < BNv) {                       // ---- A: hi-only
    const float* src = pt + (size_t)row * Dv;
    unsigned short* dst = Ah + (size_t)row * Dv;
    float4 v[3];
    float s = 0.f;
#pragma unroll
    for (int i = 0; i < 3; ++i) {
      v[i] = reinterpret_cast<const float4*>(src)[i * 64 + l];
      s += v[i].x * v[i].x + v[i].y * v[i].y + v[i].z * v[i].z + v[i].w * v[i].w;
    }
#pragma unroll
    for (int off = 32; off > 0; off >>= 1) s += __shfl_xor(s, off);
    float inv = 1.0f / fmaxf(sqrtf(s), 1e-12f);
#pragma unroll
    for (int i = 0; i < 3; ++i) {
      float a[4] = {v[i].x * inv, v[i].y * inv, v[i].z * inv, v[i].w * inv};
      *reinterpret_cast<ushort4*>(dst + i * 256 + 4 * l) =
          make_ushort4(f2bf(a[0]), f2bf(a[1]), f2bf(a[2]), f2bf(a[3]));
    }
    return;
  }
  if (row < BNv + 1024) {                // ---- B: hi|lo interleaved
    int rp = row - BNv;
    unsigned short* dst = Bhl + (size_t)rp * 1536;
    if (rp >= CKv) {                     // zero-fill pad rows
      ushort4 z = make_ushort4(0, 0, 0, 0);
#pragma unroll
      for (int i = 0; i < 3; ++i) {
        int db = 8 * i + (l >> 3);
        int base = db * 64 + 4 * (l & 7);
        *reinterpret_cast<ushort4*>(dst + base)      = z;
        *reinterpret_cast<ushort4*>(dst + base + 32) = z;
      }
      return;
    }
    const float* src = proto + (size_t)rp * Dv;
    float4 v[3];
    float s = 0.f;
#pragma unroll
    for (int i = 0; i < 3; ++i) {
      v[i] = reinterpret_cast<const float4*>(src)[i * 64 + l];
      s += v[i].x * v[i].x + v[i].y * v[i].y + v[i].z * v[i].z + v[i].w * v[i].w;
    }
#pragma unroll
    for (int off = 32; off > 0; off >>= 1) s += __shfl_xor(s, off);
    float inv = 1.0f / fmaxf(sqrtf(s), 1e-12f);
#pragma unroll
    for (int i = 0; i < 3; ++i) {
      float a[4] = {v[i].x * inv, v[i].y * inv, v[i].z * inv, v[i].w * inv};
      unsigned short hh[4], ll[4];
#pragma unroll
      for (int t = 0; t < 4; ++t) {
        hh[t] = f2bf(a[t]);
        ll[t] = f2bf(a[t] - bf2f(hh[t]));
      }
      int db = 8 * i + (l >> 3);
      int base = db * 64 + 4 * (l & 7);
      *reinterpret_cast<ushort4*>(dst + base)      = make_ushort4(hh[0], hh[1], hh[2], hh[3]);
      *reinterpret_cast<ushort4*>(dst + base + 32) = make_ushort4(ll[0], ll[1], ll[2], ll[3]);
    }
    return;
  }
  if (row < 2 * BNv + 1024) {            // ---- raw: norm only
    int rr = row - BNv - 1024;
    const float* src = raw + (size_t)rr * Dv;
    float s = 0.f;
#pragma unroll
    for (int i = 0; i < 3; ++i) {
      float4 v = reinterpret_cast<const float4*>(src)[i * 64 + l];
      s += v.x * v.x + v.y * v.y + v.z * v.z + v.w * v.w;
    }
#pragma unroll
    for (int off = 32; off > 0; off >>= 1) s += __shfl_xor(s, off);
    if (l == 0) inv_raw[rr] = 1.0f / fmaxf(sqrtf(s), 1e-12f);
  }
}

// ------------------------------------------------- MFMA 2-pass split GEMM
// logits[m][n] = dot(a_hi[m,:], b_hi[n,:]+b_lo[n,:]); fused col-max -> iplU
// BM=256 x BN=128, 512 thr / 8 waves (4M x 2N), double-buffered LDS,
// issue-early stage / single barrier per K-step.
// A LDS rows 64B (4 slots), involution slot^=(row>>1)&3 on source+read.
// B LDS rows 128B (8 slots hi|lo), involution slot^=row&7 on source+read.
#define BM 256
#define BN 128
__global__ __launch_bounds__(512, 4) void gemm_mfma_kernel(
    const unsigned short* __restrict__ Ah, const unsigned short* __restrict__ Bhl,
    float* __restrict__ Co, unsigned int* __restrict__ iplU) {
  __shared__ __align__(16) unsigned short lA[2][BM][32];
  __shared__ __align__(16) unsigned short lB[2][BN][64];
  const int tid  = threadIdx.x;
  const int wid  = tid >> 6;
  const int lane = tid & 63;
  const int wm = wid >> 1, wn = wid & 1;
  const int m0 = blockIdx.x * BM, n0 = blockIdx.y * BN;
  const int fr = lane & 15;
  const int q  = lane >> 4;

  f32x4 acc[4][4];
#pragma unroll
  for (int i = 0; i < 4; ++i)
#pragma unroll
    for (int j = 0; j < 4; ++j)
#pragma unroll
      for (int r = 0; r < 4; ++r) acc[i][j][r] = 0.f;

  // staging source pointers (swizzled global source, linear LDS dest)
  const unsigned short* srcA[2];
  const unsigned short* srcB[2];
#pragma unroll
  for (int g = 0; g < 2; ++g) {
    int ra = g * 128 + wid * 16 + (lane >> 2);
    int sa = (lane & 3) ^ ((ra >> 1) & 3);
    srcA[g] = Ah + (size_t)(m0 + ra) * Dv + sa * 8;
    int rb = g * 64 + wid * 8 + (lane >> 3);
    int sb = (lane & 7) ^ (rb & 7);
    srcB[g] = Bhl + (size_t)(n0 + rb) * 1536 + sb * 8;
  }

#define STAGE(buf, db) do {                                                            \
    __builtin_amdgcn_global_load_lds((g_u32*)(srcA[0] + (db) * 32),                    \
        (l_u32*)&lA[buf][wid * 16][0], 16, 0, 0);                                      \
    __builtin_amdgcn_global_load_lds((g_u32*)(srcA[1] + (db) * 32),                    \
        (l_u32*)&lA[buf][128 + wid * 16][0], 16, 0, 0);                                \
    __builtin_amdgcn_global_load_lds((g_u32*)(srcB[0] + (db) * 64),                    \
        (l_u32*)&lB[buf][wid * 8][0], 16, 0, 0);                                       \
    __builtin_amdgcn_global_load_lds((g_u32*)(srcB[1] + (db) * 64),                    \
        (l_u32*)&lB[buf][64 + wid * 8][0], 16, 0, 0);                                  \
  } while (0)

  const int slotA = (q ^ ((fr >> 1) & 3)) * 8;       // const per lane
  const int shB   = (q ^ (fr & 7)) * 8;
  const int slB   = ((q + 4) ^ (fr & 7)) * 8;

  STAGE(0, 0);
  __syncthreads();

  int cur = 0;
  for (int db = 0; db < 24; ++db) {
    if (db < 23) STAGE(cur ^ 1, db + 1);   // issue-early: overlaps compute below

    bf16x8 a[4];
#pragma unroll
    for (int i = 0; i < 4; ++i)
      a[i] = *reinterpret_cast<const bf16x8*>(&lA[cur][wm * 64 + i * 16 + fr][slotA]);

#pragma unroll
    for (int jh = 0; jh < 2; ++jh) {
      bf16x8 bh[2], bl[2];
#pragma unroll
      for (int jj = 0; jj < 2; ++jj) {
        const unsigned short* pb = &lB[cur][wn * 64 + (jh * 2 + jj) * 16 + fr][0];
        bh[jj] = *reinterpret_cast<const bf16x8*>(pb + shB);
        bl[jj] = *reinterpret_cast<const bf16x8*>(pb + slB);
      }
#pragma unroll
      for (int i = 0; i < 4; ++i)
#pragma unroll
        for (int jj = 0; jj < 2; ++jj) {
          int j = jh * 2 + jj;
          acc[i][j] = __builtin_amdgcn_mfma_f32_16x16x32_bf16(a[i], bh[jj], acc[i][j], 0, 0, 0);
          acc[i][j] = __builtin_amdgcn_mfma_f32_16x16x32_bf16(a[i], bl[jj], acc[i][j], 0, 0, 0);
        }
    }
    __syncthreads();   // drains vmcnt (stage) + lgkm; single barrier per K-step
    cur ^= 1;
  }
#undef STAGE

  // epilogue: nontemporal store + fused column-max for ipl
  const int b_img = m0 >> 10;
  const int mbase = m0 + wm * 64 + q * 4;
#pragma unroll
  for (int j = 0; j < 4; ++j) {
    int n = n0 + wn * 64 + j * 16 + fr;
    bool ok = (n < CKv);
    float cmax = -INFINITY;
#pragma unroll
    for (int i = 0; i < 4; ++i) {
#pragma unroll
      for (int r = 0; r < 4; ++r) {
        float v = acc[i][j][r];
        cmax = fmaxf(cmax, v);
        if (ok) __builtin_nontemporal_store(v, &Co[(size_t)(mbase + i * 16 + r) * CKv + n]);
      }
    }
    cmax = fmaxf(cmax, __shfl_xor(cmax, 16));
    cmax = fmaxf(cmax, __shfl_xor(cmax, 32));
    if (lane < 16 && ok)
      atomicMax(&iplU[(size_t)b_img * 1024 + n], fenc(cmax));
  }
}

// ---------------------------- finalize ipl + class_logits from atomic maxes
__global__ __launch_bounds__(256) void ipl_final_kernel(
    const unsigned int* __restrict__ iplU, const float* __restrict__ sa_w,
    float* __restrict__ out) {
  int b = blockIdx.x;
  int c = threadIdx.x;
  if (c >= Cv) return;
  float r[Kv];
#pragma unroll
  for (int k = 0; k < Kv; ++k) {
    r[k] = fdec(iplU[(size_t)b * 1024 + c * Kv + k]);
    out[OFF_IPL + (size_t)(b * Cv + c) * Kv + k] = r[k];
  }
  if (c < NCLS) {
    float w[Kv], wm = -INFINITY;
#pragma unroll
    for (int k = 0; k < Kv; ++k) { w[k] = sa_w[c * Kv + k]; wm = fmaxf(wm, w[k]); }
    float es = 0.f;
#pragma unroll
    for (int k = 0; k < Kv; ++k) { w[k] = expf(w[k] - wm); es += w[k]; }
    float cl = 0.f;
#pragma unroll
    for (int k = 0; k < Kv; ++k) cl += r[k] * (w[k] / es * (float)Kv);
    out[OFF_CL + b * NCLS + c] = cl / 0.2f;
  }
}

// ------------------- per-token pseudo label, softmax, argmax, threshold, A
__global__ __launch_bounds__(256) void assign_kernel(
    const float* __restrict__ logits, const int* __restrict__ labels,
    const int* __restrict__ sam, float* __restrict__ out,
    float* __restrict__ A_buf, int* __restrict__ tok_lab,
    int* __restrict__ present) {
  int n = blockIdx.x * 256 + threadIdx.x;
  if (n >= BNv) return;
  int b = n >> 10;
  int lab = (sam[n] == 1) ? labels[b] : NCLS;
  out[OFF_PSEUDO + n] = (float)lab;
  const float* p = logits + (size_t)n * CKv + lab * Kv;
  float L[Kv];
#pragma unroll
  for (int k = 0; k < Kv; ++k) L[k] = p[k];
  float mv = L[0];
  int idx = 0;
#pragma unroll
  for (int k = 1; k < Kv; ++k)
    if (L[k] > mv) { mv = L[k]; idx = k; }
  out[OFF_PART + n] = (float)(idx + lab * Kv);
  float e[Kv], s = 0.f;
#pragma unroll
  for (int k = 0; k < Kv; ++k) { e[k] = expf(L[k] - mv); s += e[k]; }
  float inv = 1.0f / s;
  float scale = (inv < 0.8f) ? 0.f : inv;
#pragma unroll
  for (int k = 0; k < Kv; ++k) A_buf[(size_t)n * Kv + k] = e[k] * scale;
  tok_lab[n] = lab;
  present[lab] = 1;
}

// --------------------------------------- per-class centroid accumulation
// grid (32 b, 3 d-chunks of 256, 4 n-chunks of 256)
__global__ __launch_bounds__(256) void accum_kernel(
    const float* __restrict__ raw, const float* __restrict__ inv_raw,
    const float* __restrict__ A_buf, const int* __restrict__ tok_lab,
    const int* __restrict__ labels, float* __restrict__ P_acc) {
  const int b = blockIdx.x;
  const int d = blockIdx.y * 256 + threadIdx.x;
  const int t0 = blockIdx.z * 256;
  __shared__ float As[256][Kv];
  __shared__ float Sc[256];
  __shared__ int   Ls[256];
  {
    int n = b * Nv + t0 + threadIdx.x;
#pragma unroll
    for (int k = 0; k < Kv; ++k) As[threadIdx.x][k] = A_buf[(size_t)n * Kv + k];
    Ls[threadIdx.x] = tok_lab[n];
    Sc[threadIdx.x] = inv_raw[n];
  }
  __syncthreads();
  float accL[Kv] = {}, accB[Kv] = {};
#pragma unroll 4
  for (int t = 0; t < 256; ++t) {
    int n2 = b * Nv + t0 + t;
    float rv = raw[(size_t)n2 * Dv + d] * Sc[t];
    if (Ls[t] == NCLS) {
#pragma unroll
      for (int k = 0; k < Kv; ++k) accB[k] = fmaf(As[t][k], rv, accB[k]);
    } else {
#pragma unroll
      for (int k = 0; k < Kv; ++k) accL[k] = fmaf(As[t][k], rv, accL[k]);
    }
  }
  int lab = labels[b];
#pragma unroll
  for (int k = 0; k < Kv; ++k) atomicAdd(&P_acc[((size_t)lab * Kv + k) * Dv + d], accL[k]);
#pragma unroll
  for (int k = 0; k < Kv; ++k) atomicAdd(&P_acc[((size_t)NCLS * Kv + k) * Dv + d], accB[k]);
}

// ------------------------------------------------------------ EMA update
__global__ __launch_bounds__(256) void pnew_kernel(
    const float* __restrict__ proto, const float* __restrict__ P_acc,
    const int* __restrict__ present, float* __restrict__ out) {
  int i = blockIdx.x * 256 + threadIdx.x;
  if (i >= Cv * Kv * Dv) return;
  int c = i / (Kv * Dv);
  float p = proto[i];
  out[OFF_PNEW + i] = present[c] ? 0.999f * p + 0.001f * P_acc[i] : p;
}

// -------------------------------------------------------------- launcher
extern "C" void kernel_launch(void* const* d_in, const int* in_sizes, int n_in,
                              void* d_out, int out_size, void* d_ws, size_t ws_size,
                              hipStream_t stream) {
  const float* pt     = (const float*)d_in[0];
  const float* raw    = (const float*)d_in[1];
  const float* proto  = (const float*)d_in[2];
  const float* sa_w   = (const float*)d_in[3];
  const int*   labels = (const int*)d_in[4];
  const int*   sam    = (const int*)d_in[5];
  float* out = (float*)d_out;

  // ---- workspace layout ----
  float* A_buf   = (float*)d_ws;                           // 163840 f
  int*   tok_lab = (int*)(A_buf + (size_t)BNv * Kv);       // 32768 i
  float* P_acc   = (float*)(tok_lab + BNv);                // 771840 f
  int*   present = (int*)(P_acc + (size_t)Cv * Kv * Dv);   // 256 i (pad)
  unsigned int* iplU = (unsigned int*)(present + 256);     // 32768 u
  float* inv_raw = (float*)(iplU + BNv);                   // 32768 f
  unsigned short* Ah  = (unsigned short*)(inv_raw + BNv);  // 32768*768 us
  unsigned short* Bhl = Ah + (size_t)BNv * Dv;             // 1024*1536 us

  // zero P_acc + present + iplU (contiguous)
  int nz = Cv * Kv * Dv + 256 + BNv;
  zero_kernel<<<(nz + 255) / 256, 256, 0, stream>>>((int*)P_acc, nz);

  prep_kernel<<<(2 * BNv + 1024) / 4, 256, 0, stream>>>(
      pt, raw, proto, Ah, Bhl, inv_raw);

  gemm_mfma_kernel<<<dim3(BNv / BM, 1024 / BN), 512, 0, stream>>>(
      Ah, Bhl, out + OFF_LOG, iplU);

  ipl_final_kernel<<<Bv, 256, 0, stream>>>(iplU, sa_w, out);

  assign_kernel<<<BNv / 256, 256, 0, stream>>>(
      out + OFF_LOG, labels, sam, out, A_buf, tok_lab, present);

  accum_kernel<<<dim3(Bv, Dv / 256, Nv / 256), 256, 0, stream>>>(
      raw, inv_raw, A_buf, tok_lab, labels, P_acc);

  pnew_kernel<<<(Cv * Kv * Dv + 255) / 256, 256, 0, stream>>>(
      proto, P_acc, present, out);
}